// Round 16
// baseline (104.154 us; speedup 1.0000x reference)
//
#include <hip/hip_runtime.h>
#include <hip/hip_bf16.h>
#include <cstdint>
#include <cstddef>

#define EMBED 768
#define NHEADS 12
#define HDIM 64
#define SEQ 1024
#define BATCH 8

typedef __attribute__((ext_vector_type(8))) short bf16x8;
typedef __attribute__((ext_vector_type(4))) float f32x4;
typedef __attribute__((ext_vector_type(16))) float f32x16;
typedef __attribute__((ext_vector_type(4))) unsigned int u32x4;

__device__ __forceinline__ short f2bf(float f) {
    union { float f; uint32_t u; } x; x.f = f;
    uint32_t r = x.u + 0x7fffu + ((x.u >> 16) & 1u);   // RNE
    return (short)(r >> 16);
}

__device__ __forceinline__ unsigned int cvt_pk_bf16(float lo, float hi) {
    unsigned int r;
    asm("v_cvt_pk_bf16_f32 %0, %1, %2" : "=v"(r) : "v"(lo), "v"(hi));
    return r;
}

// swap: a.hi32lanes <-> b.lo32lanes  (one instr fills two exchange words)
__device__ __forceinline__ void permswap(unsigned int& a, unsigned int& b) {
    asm volatile("v_permlane32_swap_b32 %0, %1" : "+v"(a), "+v"(b));
}

// async global->LDS, 16B per lane. LDS dest is wave-uniform base + lane*16.
__device__ __forceinline__ void gload_lds16(const void* g, void* l) {
    __builtin_amdgcn_global_load_lds(
        (const __attribute__((address_space(1))) unsigned int*)g,
        (__attribute__((address_space(3))) unsigned int*)l, 16, 0, 0);
}

// ---------------- fused prep: x->bf16, w_qkv^T, w_out^T (one launch) ----------
// blocks [0,3072): convert x; [3072,3504): transpose w_qkv; [3504,3648): w_out.
__global__ __launch_bounds__(256) void prep(
    const float* __restrict__ x, short* __restrict__ Xbf,
    const float* __restrict__ w_qkv, short* __restrict__ wqkvT,
    const float* __restrict__ w_out, short* __restrict__ woutT) {
    __shared__ float tile[64][65];
    const int tid = threadIdx.x;
    const int bidx = blockIdx.x;
    if (bidx < 3072) {
        size_t i = ((size_t)bidx * 256 + tid) * 8;
        float4 a = *reinterpret_cast<const float4*>(x + i);
        float4 b = *reinterpret_cast<const float4*>(x + i + 4);
        bf16x8 v;
        v[0] = f2bf(a.x); v[1] = f2bf(a.y); v[2] = f2bf(a.z); v[3] = f2bf(a.w);
        v[4] = f2bf(b.x); v[5] = f2bf(b.y); v[6] = f2bf(b.z); v[7] = f2bf(b.w);
        *reinterpret_cast<bf16x8*>(Xbf + i) = v;
        return;
    }
    const float* in;
    short* out;
    int R, C, c0, r0;
    if (bidx < 3504) {
        int bid = bidx - 3072;                 // 36 x 12
        in = w_qkv; out = wqkvT; R = 768; C = 2304;
        c0 = (bid % 36) * 64; r0 = (bid / 36) * 64;
    } else {
        int bid = bidx - 3504;                 // 12 x 12
        in = w_out; out = woutT; R = 768; C = 768;
        c0 = (bid % 12) * 64; r0 = (bid / 12) * 64;
    }
#pragma unroll
    for (int i = 0; i < 16; ++i) {
        int e = tid + 256 * i;
        int r = e >> 6, c = e & 63;
        tile[r][c] = in[(size_t)(r0 + r) * C + c0 + c];
    }
    __syncthreads();
#pragma unroll
    for (int i = 0; i < 16; ++i) {
        int e = tid + 256 * i;
        int rr = e >> 6, cc = e & 63;
        out[(size_t)(c0 + rr) * R + r0 + cc] = f2bf(tile[cc][rr]);
    }
}

// ---------------- GEMM1: Xbf(bf16) @ w_qkvT -> Q,K,Vt (bf16) ----------------
// BM=128, BN=64: 2304 blocks (exactly 3 rounds of 3/CU), 48KB LDS dbuf,
// counted vmcnt(6) pipeline (gemm_out's proven loop), qkv scatter epilogue.
__global__ __launch_bounds__(256) void gemm_qkv(
    const short* __restrict__ A, const short* __restrict__ Bt,
    const float* __restrict__ bias,
    short* __restrict__ Qo, short* __restrict__ Ko, short* __restrict__ Vto) {
    __shared__ __align__(16) char smem[49152];   // [p][A 16KB | B 8KB]; epilogue reuses 16KB
    const int tid = threadIdx.x;
    const int lane = tid & 63;
    const int wid = tid >> 6;
    const int wm = wid >> 1, wn = wid & 1;
    // bijective XCD-chunked swizzle: nwg=2304, 288/chunk, n-fast (nb=36).
    const int bid = blockIdx.x;
    const int wg = (bid & 7) * 288 + (bid >> 3);
    const int mb = wg / 36, nb = wg - mb * 36;
    const int m0 = mb * 128;
    const int n0 = nb * 64;

    const f32x4 zero4 = {0.f, 0.f, 0.f, 0.f};
    f32x4 acc[4][2];
#pragma unroll
    for (int i = 0; i < 4; ++i)
#pragma unroll
        for (int j = 0; j < 2; ++j) acc[i][j] = zero4;

    const short* Ab = A + (size_t)m0 * EMBED;
    const short* Bb = Bt + (size_t)n0 * EMBED;

    auto stage = [&](int p, int kt) {   // 6 vmem instrs/thread
        const int k0 = kt * 64;
        char* base = smem + p * 24576;
#pragma unroll
        for (int i = 0; i < 4; ++i) {   // A: 128 rows x 64 cols
            int e = i * 256 + tid;
            int r = e >> 3, cs = (e & 7) ^ (r & 7);
            gload_lds16(Ab + (size_t)r * EMBED + k0 + cs * 8,
                        base + (size_t)(i * 256 + wid * 64) * 16);
        }
#pragma unroll
        for (int i = 0; i < 2; ++i) {   // B: 64 rows x 64 cols
            int e = i * 256 + tid;
            int r = e >> 3, cs = (e & 7) ^ (r & 7);
            gload_lds16(Bb + (size_t)r * EMBED + k0 + cs * 8,
                        base + 16384 + (size_t)(i * 256 + wid * 64) * 16);
        }
    };

    stage(0, 0);
    stage(1, 1);
    asm volatile("s_waitcnt vmcnt(6)" ::: "memory");   // buf0 landed
    __builtin_amdgcn_s_barrier();
    __builtin_amdgcn_sched_barrier(0);

    for (int t = 0; t < 12; ++t) {
        const int p = t & 1;
        const char* As = smem + p * 24576;
        const char* Bs = As + 16384;
        bf16x8 af[4][2], bfv[2][2];
#pragma unroll
        for (int mi = 0; mi < 4; ++mi)
#pragma unroll
            for (int kh = 0; kh < 2; ++kh) {
                int row = wm * 64 + mi * 16 + (lane & 15);
                int c = kh * 4 + (lane >> 4);
                af[mi][kh] = *reinterpret_cast<const bf16x8*>(
                    As + row * 128 + (((c ^ (row & 7))) << 4));
            }
#pragma unroll
        for (int ni = 0; ni < 2; ++ni)
#pragma unroll
            for (int kh = 0; kh < 2; ++kh) {
                int row = wn * 32 + ni * 16 + (lane & 15);
                int c = kh * 4 + (lane >> 4);
                bfv[ni][kh] = *reinterpret_cast<const bf16x8*>(
                    Bs + row * 128 + (((c ^ (row & 7))) << 4));
            }
        asm volatile("s_waitcnt lgkmcnt(0)" ::: "memory");
        __builtin_amdgcn_s_barrier();
        __builtin_amdgcn_sched_barrier(0);
        if (t + 2 < 12) stage(p, t + 2);

        __builtin_amdgcn_s_setprio(1);
#pragma unroll
        for (int mi = 0; mi < 4; ++mi)
#pragma unroll
            for (int ni = 0; ni < 2; ++ni)
#pragma unroll
                for (int kh = 0; kh < 2; ++kh)
                    acc[mi][ni] = __builtin_amdgcn_mfma_f32_16x16x32_bf16(
                        af[mi][kh], bfv[ni][kh], acc[mi][ni], 0, 0, 0);
        __builtin_amdgcn_s_setprio(0);

        if (t + 2 < 12)
            asm volatile("s_waitcnt vmcnt(6)" ::: "memory");
        else
            asm volatile("s_waitcnt vmcnt(0)" ::: "memory");
        __builtin_amdgcn_s_barrier();
        __builtin_amdgcn_sched_barrier(0);
    }

    // epilogue. s (qkv selector) is block-constant: nb/12 (12 x 64-col blocks each).
    const int s = nb / 12;
    const int bb = m0 >> 10;
    if (s == 2) {
        // V: transpose 128x64 tile through LDS (XOR-swizzled), then store
        // rows of Vt [bh*64+d][tok] as contiguous segments. T: 64 rows x 256B.
        char* T = smem;
#pragma unroll
        for (int mi = 0; mi < 4; ++mi)
#pragma unroll
            for (int ni = 0; ni < 2; ++ni)
#pragma unroll
                for (int rp = 0; rp < 2; ++rp) {
                    int ml = wm * 64 + mi * 16 + ((lane >> 4) << 2) + rp * 2;
                    int nl = wn * 32 + ni * 16 + (lane & 15);
                    float bsv = bias[n0 + nl];
                    unsigned int w = cvt_pk_bf16(acc[mi][ni][rp * 2] + bsv,
                                                 acc[mi][ni][rp * 2 + 1] + bsv);
                    *reinterpret_cast<unsigned int*>(
                        T + nl * 256 + ((ml * 2) ^ ((nl & 7) << 4))) = w;
                }
        __syncthreads();
        // tok base is per-batch: m0 & 1023
        short* Vrow0 = Vto + ((size_t)bb * 768 + (nb - 24) * 64) * SEQ + (m0 & 1023);
#pragma unroll
        for (int it = 0; it < 4; ++it) {
            int chunk = it * 256 + tid;
            int row = chunk >> 4, k = chunk & 15;
            u32x4 v = *reinterpret_cast<const u32x4*>(
                T + row * 256 + ((k * 16) ^ ((row & 7) << 4)));
            *reinterpret_cast<u32x4*>(Vrow0 + (size_t)row * SEQ + k * 8) = v;
        }
    } else {
        short* dst = (s == 0) ? Qo : Ko;
        const float qs = (s == 0) ? 0.18033688f : 1.0f;   // SCALER*LOG2E for Q
        const int rem0 = n0 - s * 768;
#pragma unroll
        for (int mi = 0; mi < 4; ++mi)
#pragma unroll
            for (int ni = 0; ni < 2; ++ni)
#pragma unroll
                for (int r = 0; r < 4; ++r) {
                    int m = m0 + wm * 64 + mi * 16 + ((lane >> 4) << 2) + r;
                    int nl = wn * 32 + ni * 16 + (lane & 15);
                    int rem = rem0 + nl;
                    int h = rem >> 6, d = rem & 63;
                    int tok = m & 1023;
                    float v = (acc[mi][ni][r] + bias[n0 + nl]) * qs;
                    dst[(((size_t)(bb * NHEADS + h)) * SEQ + tok) * HDIM + d] = f2bf(v);
                }
    }
}

// ---------------- flash attention (r13 config: 2-wave, 64 q/wave, 3-buf) ---------
// Q,K: [BH][SEQ][64] bf16 (Q pre-scaled by 0.125*log2e); Vt: [BH][64][SEQ] bf16.
// grid (96 bh, 8 qt), 128 threads. One s_barrier per KV tile; vmcnt(8) keeps
// next tile's loads in flight; 3 buffers so stage(t+2) never aliases tile t.
__global__ __launch_bounds__(128, 2) void attn_kernel(
    const short* __restrict__ Q, const short* __restrict__ K,
    const short* __restrict__ Vt, short* __restrict__ Xo) {
    __shared__ __align__(16) char smem[49152];   // K bufs 3x8KB @0; V bufs 3x8KB @24576
    const int tid = threadIdx.x, lane = tid & 63, wid = tid >> 6;   // wid 0..1
    const int l31 = lane & 31, g = lane >> 5;
    const int bh = blockIdx.x, qt = blockIdx.y;
    const int b = bh / NHEADS, h = bh - b * NHEADS;
    const short* Qh = Q + (size_t)bh * SEQ * HDIM;
    const short* Kh = K + (size_t)bh * SEQ * HDIM;
    const short* Vh = Vt + (size_t)bh * HDIM * SEQ;
    const int q0 = qt * 128 + wid * 64;
    const int swz = (l31 & 7);

    const f32x16 zero16 = 0.f;
    bf16x8 qf[2][4];   // two q-groups of 32
#pragma unroll
    for (int qg = 0; qg < 2; ++qg)
#pragma unroll
        for (int ds = 0; ds < 4; ++ds)
            qf[qg][ds] = *reinterpret_cast<const bf16x8*>(
                Qh + (size_t)(q0 + qg * 32 + l31) * HDIM + ds * 16 + g * 8);

    f32x16 oA0 = zero16, oA1 = zero16, oB0 = zero16, oB1 = zero16;
    float lA = 0.f, lB = 0.f;

    auto stage = [&](int buf, int j0) {   // 8 vmem instrs/thread (128 threads)
#pragma unroll
        for (int i = 0; i < 4; ++i) {
            int e = i * 128 + tid;
            int r = e >> 3, cs = (e & 7) ^ (r & 7);
            char* dst = smem + (size_t)(i * 128 + wid * 64) * 16 + buf * 8192;
            gload_lds16(Kh + (size_t)(j0 + r) * HDIM + cs * 8, dst);
            gload_lds16(Vh + (size_t)r * SEQ + j0 + cs * 8, dst + 24576);
        }
    };

    stage(0, 0);
    stage(1, 64);

    for (int t = 0; t < 16; ++t) {
        const int bsel = t % 3;
        if (t < 15)
            asm volatile("s_waitcnt vmcnt(8)" ::: "memory");   // tile t landed
        else
            asm volatile("s_waitcnt vmcnt(0)" ::: "memory");
        __builtin_amdgcn_s_barrier();
        __builtin_amdgcn_sched_barrier(0);

        const char* kb = smem + bsel * 8192;
        const char* vb = smem + 24576 + bsel * 8192;

        // K frags (shared across both q-groups)
        bf16x8 kf[2][4];
#pragma unroll
        for (int s = 0; s < 2; ++s)
#pragma unroll
            for (int ds = 0; ds < 4; ++ds)
                kf[s][ds] = *reinterpret_cast<const bf16x8*>(
                    kb + (s * 32 + l31) * 128 + (((ds * 2 + g) ^ swz) << 4));

        // QK^T for both q-groups (4 independent MFMA chains)
        f32x16 sA0 = zero16, sA1 = zero16, sB0 = zero16, sB1 = zero16;
        __builtin_amdgcn_s_setprio(1);
#pragma unroll
        for (int ds = 0; ds < 4; ++ds) {
            sA0 = __builtin_amdgcn_mfma_f32_32x32x16_bf16(kf[0][ds], qf[0][ds], sA0, 0, 0, 0);
            sA1 = __builtin_amdgcn_mfma_f32_32x32x16_bf16(kf[1][ds], qf[0][ds], sA1, 0, 0, 0);
            sB0 = __builtin_amdgcn_mfma_f32_32x32x16_bf16(kf[0][ds], qf[1][ds], sB0, 0, 0, 0);
            sB1 = __builtin_amdgcn_mfma_f32_32x32x16_bf16(kf[1][ds], qf[1][ds], sB1, 0, 0, 0);
        }
        __builtin_amdgcn_s_setprio(0);

        // no-max exp2 softmax numerator + VALU row sums
        float rsA = 0.f, rsB = 0.f;
#pragma unroll
        for (int r = 0; r < 16; ++r) {
            float a0 = __builtin_amdgcn_exp2f(sA0[r]);
            float a1 = __builtin_amdgcn_exp2f(sA1[r]);
            float b0 = __builtin_amdgcn_exp2f(sB0[r]);
            float b1 = __builtin_amdgcn_exp2f(sB1[r]);
            sA0[r] = a0; sA1[r] = a1; sB0[r] = b0; sB1[r] = b1;
            rsA += a0 + a1; rsB += b0 + b1;
        }
        lA += rsA; lB += rsB;

        // P -> bf16 B-frags per group
        bf16x8 pfA[4], pfB[4];
#pragma unroll
        for (int qg = 0; qg < 2; ++qg) {
            bf16x8* pf = qg ? pfB : pfA;
#pragma unroll
            for (int s = 0; s < 2; ++s) {
                const f32x16& sv = qg ? (s ? sB1 : sB0) : (s ? sA1 : sA0);
                unsigned int pk[8];
#pragma unroll
                for (int j = 0; j < 8; ++j) pk[j] = cvt_pk_bf16(sv[2 * j], sv[2 * j + 1]);
                permswap(pk[0], pk[2]); permswap(pk[1], pk[3]);
                permswap(pk[4], pk[6]); permswap(pk[5], pk[7]);
                u32x4 wlo, whi;
                wlo[0] = pk[0]; wlo[1] = pk[1]; wlo[2] = pk[2]; wlo[3] = pk[3];
                whi[0] = pk[4]; whi[1] = pk[5]; whi[2] = pk[6]; whi[3] = pk[7];
                pf[s * 2 + 0] = __builtin_bit_cast(bf16x8, wlo);
                pf[s * 2 + 1] = __builtin_bit_cast(bf16x8, whi);
            }
        }

        // V frags (shared), then prefetch, then PV for both groups
        bf16x8 vf[4][2];
#pragma unroll
        for (int kst = 0; kst < 4; ++kst)
#pragma unroll
            for (int dsub = 0; dsub < 2; ++dsub)
                vf[kst][dsub] = *reinterpret_cast<const bf16x8*>(
                    vb + (dsub * 32 + l31) * 128 + (((kst * 2 + g) ^ swz) << 4));
        __builtin_amdgcn_sched_barrier(0);
        if (t + 2 < 16) stage((t + 2) % 3, (t + 2) * 64);

        __builtin_amdgcn_s_setprio(1);
#pragma unroll
        for (int kst = 0; kst < 4; ++kst) {
            oA0 = __builtin_amdgcn_mfma_f32_32x32x16_bf16(vf[kst][0], pfA[kst], oA0, 0, 0, 0);
            oA1 = __builtin_amdgcn_mfma_f32_32x32x16_bf16(vf[kst][1], pfA[kst], oA1, 0, 0, 0);
            oB0 = __builtin_amdgcn_mfma_f32_32x32x16_bf16(vf[kst][0], pfB[kst], oB0, 0, 0, 0);
            oB1 = __builtin_amdgcn_mfma_f32_32x32x16_bf16(vf[kst][1], pfB[kst], oB1, 0, 0, 0);
        }
        __builtin_amdgcn_s_setprio(0);
    }

    lA += __shfl_xor(lA, 32);
    lB += __shfl_xor(lB, 32);
    const float rlA = 1.0f / lA, rlB = 1.0f / lB;

    // ---- O epilogue: transpose through LDS, then coalesced 16B stores ----
    __syncthreads();                         // all waves done with K/V buffers
    char* T = smem;                          // 16KB: [128 q][64 d] bf16, swizzled
    {
        const int qx = (l31 & 7) << 4;
#pragma unroll
        for (int qg = 0; qg < 2; ++qg) {
            char* Tw = T + (wid * 64 + qg * 32 + l31) * 128;
            const float rl = qg ? rlB : rlA;
#pragma unroll
            for (int half = 0; half < 2; ++half) {
                const f32x16& ov = qg ? (half ? oB1 : oB0) : (half ? oA1 : oA0);
#pragma unroll
                for (int j = 0; j < 8; ++j) {
                    unsigned int w = cvt_pk_bf16(ov[2 * j] * rl, ov[2 * j + 1] * rl);
                    int off = 4 * (j & 1) + 16 * (j >> 1) + 8 * g + 64 * half;
                    *reinterpret_cast<unsigned int*>(Tw + (off ^ qx)) = w;
                }
            }
        }
    }
    __syncthreads();
    const int q0b = qt * 128;
    short* xbase = Xo + ((size_t)b * SEQ + q0b) * EMBED + h * HDIM;
#pragma unroll
    for (int it = 0; it < 8; ++it) {
        int chunk = it * 128 + tid;
        int row = chunk >> 3, k = chunk & 7;
        u32x4 v = *reinterpret_cast<const u32x4*>(
            T + row * 128 + ((k * 16) ^ ((row & 7) << 4)));
        *reinterpret_cast<u32x4*>(xbase + (size_t)row * EMBED + k * 8) = v;
    }
}

// ---------------- GEMM3: xattn(bf16) @ w_outT -> out (fp32) ----------------
// BM=128, BN=64: 768 blocks (exactly 3/CU), 48KB LDS dbuf, counted vmcnt(6).
__global__ __launch_bounds__(256) void gemm_out(
    const short* __restrict__ A, const short* __restrict__ Bt,
    const float* __restrict__ bias, float* __restrict__ C) {
    __shared__ __align__(16) char smem[49152];   // [p][A 16KB | B 8KB]
    const int tid = threadIdx.x;
    const int lane = tid & 63;
    const int wid = tid >> 6;
    const int wm = wid >> 1, wn = wid & 1;
    // bijective XCD-chunked swizzle: nwg=768, 96/chunk, n-fast (nb=12).
    const int bid = blockIdx.x;
    const int wg = (bid & 7) * 96 + (bid >> 3);
    const int mb = wg / 12, nb = wg - mb * 12;
    const int m0 = mb * 128;
    const int n0 = nb * 64;

    const f32x4 zero4 = {0.f, 0.f, 0.f, 0.f};
    f32x4 acc[4][2];
#pragma unroll
    for (int i = 0; i < 4; ++i)
#pragma unroll
        for (int j = 0; j < 2; ++j) acc[i][j] = zero4;

    const short* Ab = A + (size_t)m0 * EMBED;
    const short* Bb = Bt + (size_t)n0 * EMBED;

    auto stage = [&](int p, int kt) {   // 6 vmem instrs/thread
        const int k0 = kt * 64;
        char* base = smem + p * 24576;
#pragma unroll
        for (int i = 0; i < 4; ++i) {   // A: 128 rows x 64 cols
            int e = i * 256 + tid;
            int r = e >> 3, cs = (e & 7) ^ (r & 7);
            gload_lds16(Ab + (size_t)r * EMBED + k0 + cs * 8,
                        base + (size_t)(i * 256 + wid * 64) * 16);
        }
#pragma unroll
        for (int i = 0; i < 2; ++i) {   // B: 64 rows x 64 cols
            int e = i * 256 + tid;
            int r = e >> 3, cs = (e & 7) ^ (r & 7);
            gload_lds16(Bb + (size_t)r * EMBED + k0 + cs * 8,
                        base + 16384 + (size_t)(i * 256 + wid * 64) * 16);
        }
    };

    stage(0, 0);
    stage(1, 1);
    asm volatile("s_waitcnt vmcnt(6)" ::: "memory");   // buf0 landed
    __builtin_amdgcn_s_barrier();
    __builtin_amdgcn_sched_barrier(0);

    for (int t = 0; t < 12; ++t) {
        const int p = t & 1;
        const char* As = smem + p * 24576;
        const char* Bs = As + 16384;
        bf16x8 af[4][2], bfv[2][2];
#pragma unroll
        for (int mi = 0; mi < 4; ++mi)
#pragma unroll
            for (int kh = 0; kh < 2; ++kh) {
                int row = wm * 64 + mi * 16 + (lane & 15);
                int c = kh * 4 + (lane >> 4);
                af[mi][kh] = *reinterpret_cast<const bf16x8*>(
                    As + row * 128 + (((c ^ (row & 7))) << 4));
            }
#pragma unroll
        for (int ni = 0; ni < 2; ++ni)
#pragma unroll
            for (int kh = 0; kh < 2; ++kh) {
                int row = wn * 32 + ni * 16 + (lane & 15);
                int c = kh * 4 + (lane >> 4);
                bfv[ni][kh] = *reinterpret_cast<const bf16x8*>(
                    Bs + row * 128 + (((c ^ (row & 7))) << 4));
            }
        asm volatile("s_waitcnt lgkmcnt(0)" ::: "memory");
        __builtin_amdgcn_s_barrier();
        __builtin_amdgcn_sched_barrier(0);
        if (t + 2 < 12) stage(p, t + 2);

        __builtin_amdgcn_s_setprio(1);
#pragma unroll
        for (int mi = 0; mi < 4; ++mi)
#pragma unroll
            for (int ni = 0; ni < 2; ++ni)
#pragma unroll
                for (int kh = 0; kh < 2; ++kh)
                    acc[mi][ni] = __builtin_amdgcn_mfma_f32_16x16x32_bf16(
                        af[mi][kh], bfv[ni][kh], acc[mi][ni], 0, 0, 0);
        __builtin_amdgcn_s_setprio(0);

        if (t + 2 < 12)
            asm volatile("s_waitcnt vmcnt(6)" ::: "memory");
        else
            asm volatile("s_waitcnt vmcnt(0)" ::: "memory");
        __builtin_amdgcn_s_barrier();
        __builtin_amdgcn_sched_barrier(0);
    }

#pragma unroll
    for (int mi = 0; mi < 4; ++mi)
#pragma unroll
        for (int ni = 0; ni < 2; ++ni)
#pragma unroll
            for (int r = 0; r < 4; ++r) {
                int m = m0 + wm * 64 + mi * 16 + ((lane >> 4) << 2) + r;
                int n = n0 + wn * 32 + ni * 16 + (lane & 15);
                C[(size_t)m * EMBED + n] = acc[mi][ni][r] + bias[n];
            }
}

// ---------------- launch ----------------
extern "C" void kernel_launch(void* const* d_in, const int* in_sizes, int n_in,
                              void* d_out, int out_size, void* d_ws, size_t ws_size,
                              hipStream_t stream) {
    const float* x      = (const float*)d_in[0];
    const float* w_qkv  = (const float*)d_in[1];
    const float* b_qkv  = (const float*)d_in[2];
    const float* w_out  = (const float*)d_in[3];
    const float* b_out  = (const float*)d_in[4];
    float* out = (float*)d_out;
    char* ws = (char*)d_ws;

    short* wqkvT = (short*)(ws + 0);            //  2304*768*2
    short* woutT = (short*)(ws + 3538944);      //   768*768*2
    short* Qb    = (short*)(ws + 4718592);      // 96*1024*64*2 each
    short* Kb    = (short*)(ws + 17301504);
    short* Vtb   = (short*)(ws + 29884416);
    short* Xbf   = (short*)(ws + 42467328);     // x as bf16 (prep..gemm1), then
    short* Xab   = (short*)(ws + 42467328);     // reused as attn output

    prep<<<dim3(3648), 256, 0, stream>>>(x, Xbf, w_qkv, wqkvT, w_out, woutT);
    gemm_qkv<<<dim3(2304), 256, 0, stream>>>(Xbf, wqkvT, b_qkv, Qb, Kb, Vtb);
    attn_kernel<<<dim3(96, 8), 128, 0, stream>>>(Qb, Kb, Vtb, Xab);
    gemm_out<<<dim3(768), 256, 0, stream>>>(Xab, woutT, b_out, out);
}

// Round 17
// 101.554 us; speedup vs baseline: 1.0256x; 1.0256x over previous
//
#include <hip/hip_runtime.h>
#include <hip/hip_bf16.h>
#include <cstdint>
#include <cstddef>

#define EMBED 768
#define NHEADS 12
#define HDIM 64
#define SEQ 1024
#define BATCH 8

typedef __attribute__((ext_vector_type(8))) short bf16x8;
typedef __attribute__((ext_vector_type(4))) float f32x4;
typedef __attribute__((ext_vector_type(16))) float f32x16;
typedef __attribute__((ext_vector_type(4))) unsigned int u32x4;

__device__ __forceinline__ short f2bf(float f) {
    union { float f; uint32_t u; } x; x.f = f;
    uint32_t r = x.u + 0x7fffu + ((x.u >> 16) & 1u);   // RNE
    return (short)(r >> 16);
}

__device__ __forceinline__ unsigned int cvt_pk_bf16(float lo, float hi) {
    unsigned int r;
    asm("v_cvt_pk_bf16_f32 %0, %1, %2" : "=v"(r) : "v"(lo), "v"(hi));
    return r;
}

// swap: a.hi32lanes <-> b.lo32lanes  (one instr fills two exchange words)
__device__ __forceinline__ void permswap(unsigned int& a, unsigned int& b) {
    asm volatile("v_permlane32_swap_b32 %0, %1" : "+v"(a), "+v"(b));
}

// async global->LDS, 16B per lane. LDS dest is wave-uniform base + lane*16.
__device__ __forceinline__ void gload_lds16(const void* g, void* l) {
    __builtin_amdgcn_global_load_lds(
        (const __attribute__((address_space(1))) unsigned int*)g,
        (__attribute__((address_space(3))) unsigned int*)l, 16, 0, 0);
}

// ---------------- fused prep: x->bf16, w_qkv^T, w_out^T (one launch) ----------
// blocks [0,3072): convert x; [3072,3504): transpose w_qkv; [3504,3648): w_out.
__global__ __launch_bounds__(256) void prep(
    const float* __restrict__ x, short* __restrict__ Xbf,
    const float* __restrict__ w_qkv, short* __restrict__ wqkvT,
    const float* __restrict__ w_out, short* __restrict__ woutT) {
    __shared__ float tile[64][65];
    const int tid = threadIdx.x;
    const int bidx = blockIdx.x;
    if (bidx < 3072) {
        size_t i = ((size_t)bidx * 256 + tid) * 8;
        float4 a = *reinterpret_cast<const float4*>(x + i);
        float4 b = *reinterpret_cast<const float4*>(x + i + 4);
        bf16x8 v;
        v[0] = f2bf(a.x); v[1] = f2bf(a.y); v[2] = f2bf(a.z); v[3] = f2bf(a.w);
        v[4] = f2bf(b.x); v[5] = f2bf(b.y); v[6] = f2bf(b.z); v[7] = f2bf(b.w);
        *reinterpret_cast<bf16x8*>(Xbf + i) = v;
        return;
    }
    const float* in;
    short* out;
    int R, C, c0, r0;
    if (bidx < 3504) {
        int bid = bidx - 3072;                 // 36 x 12
        in = w_qkv; out = wqkvT; R = 768; C = 2304;
        c0 = (bid % 36) * 64; r0 = (bid / 36) * 64;
    } else {
        int bid = bidx - 3504;                 // 12 x 12
        in = w_out; out = woutT; R = 768; C = 768;
        c0 = (bid % 12) * 64; r0 = (bid / 12) * 64;
    }
#pragma unroll
    for (int i = 0; i < 16; ++i) {
        int e = tid + 256 * i;
        int r = e >> 6, c = e & 63;
        tile[r][c] = in[(size_t)(r0 + r) * C + c0 + c];
    }
    __syncthreads();
#pragma unroll
    for (int i = 0; i < 16; ++i) {
        int e = tid + 256 * i;
        int rr = e >> 6, cc = e & 63;
        out[(size_t)(c0 + rr) * R + r0 + cc] = f2bf(tile[cc][rr]);
    }
}

// ---------------- GEMM1: Xbf(bf16) @ w_qkvT -> Q,K,Vt (bf16) ----------------
// 128x128 tile, 512 threads / 8 waves (4M x 2N, 32x64 per wave), 64KB dbuf LDS,
// counted vmcnt(4) pipeline -> 2 blocks/CU x 8 waves = 16 waves/CU.
__global__ __launch_bounds__(512) void gemm_qkv(
    const short* __restrict__ A, const short* __restrict__ Bt,
    const float* __restrict__ bias,
    short* __restrict__ Qo, short* __restrict__ Ko, short* __restrict__ Vto) {
    __shared__ __align__(16) char smem[65536];   // [p][A 16KB | B 16KB]; epilogue reuses 32KB
    const int tid = threadIdx.x;
    const int lane = tid & 63;
    const int wid = tid >> 6;            // 0..7
    const int wm = wid >> 1, wn = wid & 1;
    // bijective XCD-chunked swizzle: nwg=1152, 144/chunk, n-fast.
    const int bid = blockIdx.x;
    const int wg = (bid & 7) * 144 + (bid >> 3);
    const int mb = wg / 18, nb = wg - mb * 18;
    const int m0 = mb * 128;
    const int n0 = nb * 128;

    const f32x4 zero4 = {0.f, 0.f, 0.f, 0.f};
    f32x4 acc[2][4];
#pragma unroll
    for (int i = 0; i < 2; ++i)
#pragma unroll
        for (int j = 0; j < 4; ++j) acc[i][j] = zero4;

    const short* Ab = A + (size_t)m0 * EMBED;
    const short* Bb = Bt + (size_t)n0 * EMBED;

    auto stage = [&](int p, int kt) {   // 4 vmem instrs/thread (512 threads)
        const int k0 = kt * 64;
        char* base = smem + p * 32768;
#pragma unroll
        for (int i = 0; i < 2; ++i) {
            int e = i * 512 + tid;
            int r = e >> 3, cs = (e & 7) ^ (r & 7);
            char* dst = base + (size_t)(i * 512 + wid * 64) * 16;
            gload_lds16(Ab + (size_t)r * EMBED + k0 + cs * 8, dst);
            gload_lds16(Bb + (size_t)r * EMBED + k0 + cs * 8, dst + 16384);
        }
    };

    stage(0, 0);
    stage(1, 1);
    asm volatile("s_waitcnt vmcnt(4)" ::: "memory");   // buf0 landed
    __builtin_amdgcn_s_barrier();
    __builtin_amdgcn_sched_barrier(0);

    for (int t = 0; t < 12; ++t) {
        const int p = t & 1;
        const char* As = smem + p * 32768;
        const char* Bs = As + 16384;
        bf16x8 af[2][2], bfv[4][2];
#pragma unroll
        for (int mi = 0; mi < 2; ++mi)
#pragma unroll
            for (int kh = 0; kh < 2; ++kh) {
                int row = wm * 32 + mi * 16 + (lane & 15);
                int c = kh * 4 + (lane >> 4);
                af[mi][kh] = *reinterpret_cast<const bf16x8*>(
                    As + row * 128 + (((c ^ (row & 7))) << 4));
            }
#pragma unroll
        for (int ni = 0; ni < 4; ++ni)
#pragma unroll
            for (int kh = 0; kh < 2; ++kh) {
                int row = wn * 64 + ni * 16 + (lane & 15);
                int c = kh * 4 + (lane >> 4);
                bfv[ni][kh] = *reinterpret_cast<const bf16x8*>(
                    Bs + row * 128 + (((c ^ (row & 7))) << 4));
            }
        asm volatile("s_waitcnt lgkmcnt(0)" ::: "memory");   // my reads of buf[p] done
        __builtin_amdgcn_s_barrier();                        // everyone's reads done
        __builtin_amdgcn_sched_barrier(0);
        if (t + 2 < 12) stage(p, t + 2);                     // refill freed buffer

        __builtin_amdgcn_s_setprio(1);
#pragma unroll
        for (int mi = 0; mi < 2; ++mi)
#pragma unroll
            for (int ni = 0; ni < 4; ++ni)
#pragma unroll
                for (int kh = 0; kh < 2; ++kh)
                    acc[mi][ni] = __builtin_amdgcn_mfma_f32_16x16x32_bf16(
                        af[mi][kh], bfv[ni][kh], acc[mi][ni], 0, 0, 0);
        __builtin_amdgcn_s_setprio(0);

        if (t + 2 < 12)
            asm volatile("s_waitcnt vmcnt(4)" ::: "memory"); // tile t+1 landed, t+2 in flight
        else
            asm volatile("s_waitcnt vmcnt(0)" ::: "memory"); // tail drain
        __builtin_amdgcn_s_barrier();                        // tile t+1 visible to all
        __builtin_amdgcn_sched_barrier(0);
    }

    // epilogue. s (qkv selector) is block-constant: nb/6.
    const int s = nb / 6;
    const int bb = m0 >> 10;
    if (s == 2) {
        // V: transpose 128x128 tile through LDS (XOR-swizzled), then store
        // rows of Vt [bh*64+d][tok] as 256B-contiguous segments.
        char* T = smem;
#pragma unroll
        for (int mi = 0; mi < 2; ++mi)
#pragma unroll
            for (int ni = 0; ni < 4; ++ni)
#pragma unroll
                for (int rp = 0; rp < 2; ++rp) {
                    int ml = wm * 32 + mi * 16 + ((lane >> 4) << 2) + rp * 2;
                    int nl = wn * 64 + ni * 16 + (lane & 15);
                    float bsv = bias[n0 + nl];
                    unsigned int w = cvt_pk_bf16(acc[mi][ni][rp * 2] + bsv,
                                                 acc[mi][ni][rp * 2 + 1] + bsv);
                    *reinterpret_cast<unsigned int*>(
                        T + nl * 256 + ((ml * 2) ^ ((nl & 7) << 4))) = w;
                }
        __syncthreads();
        // tok base is per-batch: m0 & 1023
        short* Vrow0 = Vto + ((size_t)bb * 768 + (nb - 12) * 128) * SEQ + (m0 & 1023);
#pragma unroll
        for (int it = 0; it < 4; ++it) {
            int chunk = it * 512 + tid;
            int row = chunk >> 4, k = chunk & 15;
            u32x4 v = *reinterpret_cast<const u32x4*>(
                T + row * 256 + ((k * 16) ^ ((row & 7) << 4)));
            *reinterpret_cast<u32x4*>(Vrow0 + (size_t)row * SEQ + k * 8) = v;
        }
    } else {
        short* dst = (s == 0) ? Qo : Ko;
        const float qs = (s == 0) ? 0.18033688f : 1.0f;   // SCALER*LOG2E for Q
        const int rem0 = n0 - s * 768;
#pragma unroll
        for (int mi = 0; mi < 2; ++mi)
#pragma unroll
            for (int ni = 0; ni < 4; ++ni)
#pragma unroll
                for (int r = 0; r < 4; ++r) {
                    int m = m0 + wm * 32 + mi * 16 + ((lane >> 4) << 2) + r;
                    int nl = wn * 64 + ni * 16 + (lane & 15);
                    int rem = rem0 + nl;
                    int h = rem >> 6, d = rem & 63;
                    int tok = m & 1023;
                    float v = (acc[mi][ni][r] + bias[n0 + nl]) * qs;
                    dst[(((size_t)(bb * NHEADS + h)) * SEQ + tok) * HDIM + d] = f2bf(v);
                }
    }
}

// ---------------- flash attention (r13 config: 2-wave, 64 q/wave, 3-buf) ---------
// Q,K: [BH][SEQ][64] bf16 (Q pre-scaled by 0.125*log2e); Vt: [BH][64][SEQ] bf16.
// grid (96 bh, 8 qt), 128 threads. One s_barrier per KV tile; vmcnt(8) keeps
// next tile's loads in flight; 3 buffers so stage(t+2) never aliases tile t.
__global__ __launch_bounds__(128, 2) void attn_kernel(
    const short* __restrict__ Q, const short* __restrict__ K,
    const short* __restrict__ Vt, short* __restrict__ Xo) {
    __shared__ __align__(16) char smem[49152];   // K bufs 3x8KB @0; V bufs 3x8KB @24576
    const int tid = threadIdx.x, lane = tid & 63, wid = tid >> 6;   // wid 0..1
    const int l31 = lane & 31, g = lane >> 5;
    const int bh = blockIdx.x, qt = blockIdx.y;
    const int b = bh / NHEADS, h = bh - b * NHEADS;
    const short* Qh = Q + (size_t)bh * SEQ * HDIM;
    const short* Kh = K + (size_t)bh * SEQ * HDIM;
    const short* Vh = Vt + (size_t)bh * HDIM * SEQ;
    const int q0 = qt * 128 + wid * 64;
    const int swz = (l31 & 7);

    const f32x16 zero16 = 0.f;
    bf16x8 qf[2][4];   // two q-groups of 32
#pragma unroll
    for (int qg = 0; qg < 2; ++qg)
#pragma unroll
        for (int ds = 0; ds < 4; ++ds)
            qf[qg][ds] = *reinterpret_cast<const bf16x8*>(
                Qh + (size_t)(q0 + qg * 32 + l31) * HDIM + ds * 16 + g * 8);

    f32x16 oA0 = zero16, oA1 = zero16, oB0 = zero16, oB1 = zero16;
    float lA = 0.f, lB = 0.f;

    auto stage = [&](int buf, int j0) {   // 8 vmem instrs/thread (128 threads)
#pragma unroll
        for (int i = 0; i < 4; ++i) {
            int e = i * 128 + tid;
            int r = e >> 3, cs = (e & 7) ^ (r & 7);
            char* dst = smem + (size_t)(i * 128 + wid * 64) * 16 + buf * 8192;
            gload_lds16(Kh + (size_t)(j0 + r) * HDIM + cs * 8, dst);
            gload_lds16(Vh + (size_t)r * SEQ + j0 + cs * 8, dst + 24576);
        }
    };

    stage(0, 0);
    stage(1, 64);

    for (int t = 0; t < 16; ++t) {
        const int bsel = t % 3;
        if (t < 15)
            asm volatile("s_waitcnt vmcnt(8)" ::: "memory");   // tile t landed
        else
            asm volatile("s_waitcnt vmcnt(0)" ::: "memory");
        __builtin_amdgcn_s_barrier();
        __builtin_amdgcn_sched_barrier(0);

        const char* kb = smem + bsel * 8192;
        const char* vb = smem + 24576 + bsel * 8192;

        // K frags (shared across both q-groups)
        bf16x8 kf[2][4];
#pragma unroll
        for (int s = 0; s < 2; ++s)
#pragma unroll
            for (int ds = 0; ds < 4; ++ds)
                kf[s][ds] = *reinterpret_cast<const bf16x8*>(
                    kb + (s * 32 + l31) * 128 + (((ds * 2 + g) ^ swz) << 4));

        // QK^T for both q-groups (4 independent MFMA chains)
        f32x16 sA0 = zero16, sA1 = zero16, sB0 = zero16, sB1 = zero16;
        __builtin_amdgcn_s_setprio(1);
#pragma unroll
        for (int ds = 0; ds < 4; ++ds) {
            sA0 = __builtin_amdgcn_mfma_f32_32x32x16_bf16(kf[0][ds], qf[0][ds], sA0, 0, 0, 0);
            sA1 = __builtin_amdgcn_mfma_f32_32x32x16_bf16(kf[1][ds], qf[0][ds], sA1, 0, 0, 0);
            sB0 = __builtin_amdgcn_mfma_f32_32x32x16_bf16(kf[0][ds], qf[1][ds], sB0, 0, 0, 0);
            sB1 = __builtin_amdgcn_mfma_f32_32x32x16_bf16(kf[1][ds], qf[1][ds], sB1, 0, 0, 0);
        }
        __builtin_amdgcn_s_setprio(0);

        // no-max exp2 softmax numerator + VALU row sums
        float rsA = 0.f, rsB = 0.f;
#pragma unroll
        for (int r = 0; r < 16; ++r) {
            float a0 = __builtin_amdgcn_exp2f(sA0[r]);
            float a1 = __builtin_amdgcn_exp2f(sA1[r]);
            float b0 = __builtin_amdgcn_exp2f(sB0[r]);
            float b1 = __builtin_amdgcn_exp2f(sB1[r]);
            sA0[r] = a0; sA1[r] = a1; sB0[r] = b0; sB1[r] = b1;
            rsA += a0 + a1; rsB += b0 + b1;
        }
        lA += rsA; lB += rsB;

        // P -> bf16 B-frags per group
        bf16x8 pfA[4], pfB[4];
#pragma unroll
        for (int qg = 0; qg < 2; ++qg) {
            bf16x8* pf = qg ? pfB : pfA;
#pragma unroll
            for (int s = 0; s < 2; ++s) {
                const f32x16& sv = qg ? (s ? sB1 : sB0) : (s ? sA1 : sA0);
                unsigned int pk[8];
#pragma unroll
                for (int j = 0; j < 8; ++j) pk[j] = cvt_pk_bf16(sv[2 * j], sv[2 * j + 1]);
                permswap(pk[0], pk[2]); permswap(pk[1], pk[3]);
                permswap(pk[4], pk[6]); permswap(pk[5], pk[7]);
                u32x4 wlo, whi;
                wlo[0] = pk[0]; wlo[1] = pk[1]; wlo[2] = pk[2]; wlo[3] = pk[3];
                whi[0] = pk[4]; whi[1] = pk[5]; whi[2] = pk[6]; whi[3] = pk[7];
                pf[s * 2 + 0] = __builtin_bit_cast(bf16x8, wlo);
                pf[s * 2 + 1] = __builtin_bit_cast(bf16x8, whi);
            }
        }

        // V frags (shared), then prefetch, then PV for both groups
        bf16x8 vf[4][2];
#pragma unroll
        for (int kst = 0; kst < 4; ++kst)
#pragma unroll
            for (int dsub = 0; dsub < 2; ++dsub)
                vf[kst][dsub] = *reinterpret_cast<const bf16x8*>(
                    vb + (dsub * 32 + l31) * 128 + (((kst * 2 + g) ^ swz) << 4));
        __builtin_amdgcn_sched_barrier(0);
        if (t + 2 < 16) stage((t + 2) % 3, (t + 2) * 64);

        __builtin_amdgcn_s_setprio(1);
#pragma unroll
        for (int kst = 0; kst < 4; ++kst) {
            oA0 = __builtin_amdgcn_mfma_f32_32x32x16_bf16(vf[kst][0], pfA[kst], oA0, 0, 0, 0);
            oA1 = __builtin_amdgcn_mfma_f32_32x32x16_bf16(vf[kst][1], pfA[kst], oA1, 0, 0, 0);
            oB0 = __builtin_amdgcn_mfma_f32_32x32x16_bf16(vf[kst][0], pfB[kst], oB0, 0, 0, 0);
            oB1 = __builtin_amdgcn_mfma_f32_32x32x16_bf16(vf[kst][1], pfB[kst], oB1, 0, 0, 0);
        }
        __builtin_amdgcn_s_setprio(0);
    }

    lA += __shfl_xor(lA, 32);
    lB += __shfl_xor(lB, 32);
    const float rlA = 1.0f / lA, rlB = 1.0f / lB;

    // ---- O epilogue: transpose through LDS, then coalesced 16B stores ----
    __syncthreads();                         // all waves done with K/V buffers
    char* T = smem;                          // 16KB: [128 q][64 d] bf16, swizzled
    {
        const int qx = (l31 & 7) << 4;
#pragma unroll
        for (int qg = 0; qg < 2; ++qg) {
            char* Tw = T + (wid * 64 + qg * 32 + l31) * 128;
            const float rl = qg ? rlB : rlA;
#pragma unroll
            for (int half = 0; half < 2; ++half) {
                const f32x16& ov = qg ? (half ? oB1 : oB0) : (half ? oA1 : oA0);
#pragma unroll
                for (int j = 0; j < 8; ++j) {
                    unsigned int w = cvt_pk_bf16(ov[2 * j] * rl, ov[2 * j + 1] * rl);
                    int off = 4 * (j & 1) + 16 * (j >> 1) + 8 * g + 64 * half;
                    *reinterpret_cast<unsigned int*>(Tw + (off ^ qx)) = w;
                }
            }
        }
    }
    __syncthreads();
    const int q0b = qt * 128;
    short* xbase = Xo + ((size_t)b * SEQ + q0b) * EMBED + h * HDIM;
#pragma unroll
    for (int it = 0; it < 8; ++it) {
        int chunk = it * 128 + tid;
        int row = chunk >> 3, k = chunk & 7;
        u32x4 v = *reinterpret_cast<const u32x4*>(
            T + row * 128 + ((k * 16) ^ ((row & 7) << 4)));
        *reinterpret_cast<u32x4*>(xbase + (size_t)row * EMBED + k * 8) = v;
    }
}

// ---------------- GEMM3: xattn(bf16) @ w_outT -> out (fp32) ----------------
// BM=128, BN=64: 768 blocks (exactly 3/CU), 48KB LDS dbuf, counted vmcnt(6).
__global__ __launch_bounds__(256) void gemm_out(
    const short* __restrict__ A, const short* __restrict__ Bt,
    const float* __restrict__ bias, float* __restrict__ C) {
    __shared__ __align__(16) char smem[49152];   // [p][A 16KB | B 8KB]
    const int tid = threadIdx.x;
    const int lane = tid & 63;
    const int wid = tid >> 6;
    const int wm = wid >> 1, wn = wid & 1;
    // bijective XCD-chunked swizzle: nwg=768, 96/chunk, n-fast (nb=12).
    const int bid = blockIdx.x;
    const int wg = (bid & 7) * 96 + (bid >> 3);
    const int mb = wg / 12, nb = wg - mb * 12;
    const int m0 = mb * 128;
    const int n0 = nb * 64;

    const f32x4 zero4 = {0.f, 0.f, 0.f, 0.f};
    f32x4 acc[4][2];
#pragma unroll
    for (int i = 0; i < 4; ++i)
#pragma unroll
        for (int j = 0; j < 2; ++j) acc[i][j] = zero4;

    const short* Ab = A + (size_t)m0 * EMBED;
    const short* Bb = Bt + (size_t)n0 * EMBED;

    auto stage = [&](int p, int kt) {   // 6 vmem instrs/thread
        const int k0 = kt * 64;
        char* base = smem + p * 24576;
#pragma unroll
        for (int i = 0; i < 4; ++i) {   // A: 128 rows x 64 cols
            int e = i * 256 + tid;
            int r = e >> 3, cs = (e & 7) ^ (r & 7);
            gload_lds16(Ab + (size_t)r * EMBED + k0 + cs * 8,
                        base + (size_t)(i * 256 + wid * 64) * 16);
        }
#pragma unroll
        for (int i = 0; i < 2; ++i) {   // B: 64 rows x 64 cols
            int e = i * 256 + tid;
            int r = e >> 3, cs = (e & 7) ^ (r & 7);
            gload_lds16(Bb + (size_t)r * EMBED + k0 + cs * 8,
                        base + 16384 + (size_t)(i * 256 + wid * 64) * 16);
        }
    };

    stage(0, 0);
    stage(1, 1);
    asm volatile("s_waitcnt vmcnt(6)" ::: "memory");   // buf0 landed
    __builtin_amdgcn_s_barrier();
    __builtin_amdgcn_sched_barrier(0);

    for (int t = 0; t < 12; ++t) {
        const int p = t & 1;
        const char* As = smem + p * 24576;
        const char* Bs = As + 16384;
        bf16x8 af[4][2], bfv[2][2];
#pragma unroll
        for (int mi = 0; mi < 4; ++mi)
#pragma unroll
            for (int kh = 0; kh < 2; ++kh) {
                int row = wm * 64 + mi * 16 + (lane & 15);
                int c = kh * 4 + (lane >> 4);
                af[mi][kh] = *reinterpret_cast<const bf16x8*>(
                    As + row * 128 + (((c ^ (row & 7))) << 4));
            }
#pragma unroll
        for (int ni = 0; ni < 2; ++ni)
#pragma unroll
            for (int kh = 0; kh < 2; ++kh) {
                int row = wn * 32 + ni * 16 + (lane & 15);
                int c = kh * 4 + (lane >> 4);
                bfv[ni][kh] = *reinterpret_cast<const bf16x8*>(
                    Bs + row * 128 + (((c ^ (row & 7))) << 4));
            }
        asm volatile("s_waitcnt lgkmcnt(0)" ::: "memory");
        __builtin_amdgcn_s_barrier();
        __builtin_amdgcn_sched_barrier(0);
        if (t + 2 < 12) stage(p, t + 2);

        __builtin_amdgcn_s_setprio(1);
#pragma unroll
        for (int mi = 0; mi < 4; ++mi)
#pragma unroll
            for (int ni = 0; ni < 2; ++ni)
#pragma unroll
                for (int kh = 0; kh < 2; ++kh)
                    acc[mi][ni] = __builtin_amdgcn_mfma_f32_16x16x32_bf16(
                        af[mi][kh], bfv[ni][kh], acc[mi][ni], 0, 0, 0);
        __builtin_amdgcn_s_setprio(0);

        if (t + 2 < 12)
            asm volatile("s_waitcnt vmcnt(6)" ::: "memory");
        else
            asm volatile("s_waitcnt vmcnt(0)" ::: "memory");
        __builtin_amdgcn_s_barrier();
        __builtin_amdgcn_sched_barrier(0);
    }

#pragma unroll
    for (int mi = 0; mi < 4; ++mi)
#pragma unroll
        for (int ni = 0; ni < 2; ++ni)
#pragma unroll
            for (int r = 0; r < 4; ++r) {
                int m = m0 + wm * 64 + mi * 16 + ((lane >> 4) << 2) + r;
                int n = n0 + wn * 32 + ni * 16 + (lane & 15);
                C[(size_t)m * EMBED + n] = acc[mi][ni][r] + bias[n];
            }
}

// ---------------- launch ----------------
extern "C" void kernel_launch(void* const* d_in, const int* in_sizes, int n_in,
                              void* d_out, int out_size, void* d_ws, size_t ws_size,
                              hipStream_t stream) {
    const float* x      = (const float*)d_in[0];
    const float* w_qkv  = (const float*)d_in[1];
    const float* b_qkv  = (const float*)d_in[2];
    const float* w_out  = (const float*)d_in[3];
    const float* b_out  = (const float*)d_in[4];
    float* out = (float*)d_out;
    char* ws = (char*)d_ws;

    short* wqkvT = (short*)(ws + 0);            //  2304*768*2
    short* woutT = (short*)(ws + 3538944);      //   768*768*2
    short* Qb    = (short*)(ws + 4718592);      // 96*1024*64*2 each
    short* Kb    = (short*)(ws + 17301504);
    short* Vtb   = (short*)(ws + 29884416);
    short* Xbf   = (short*)(ws + 42467328);     // x as bf16 (prep..gemm1), then
    short* Xab   = (short*)(ws + 42467328);     // reused as attn output

    prep<<<dim3(3648), 256, 0, stream>>>(x, Xbf, w_qkv, wqkvT, w_out, woutT);
    gemm_qkv<<<dim3(1152), 512, 0, stream>>>(Xbf, wqkvT, b_qkv, Qb, Kb, Vtb);
    attn_kernel<<<dim3(96, 8), 128, 0, stream>>>(Qb, Kb, Vtb, Xab);
    gemm_out<<<dim3(768), 256, 0, stream>>>(Xab, woutT, b_out, out);
}

// Round 18
// 99.763 us; speedup vs baseline: 1.0440x; 1.0180x over previous
//
#include <hip/hip_runtime.h>
#include <hip/hip_bf16.h>
#include <cstdint>
#include <cstddef>

#define EMBED 768
#define NHEADS 12
#define HDIM 64
#define SEQ 1024
#define BATCH 8

typedef __attribute__((ext_vector_type(8))) short bf16x8;
typedef __attribute__((ext_vector_type(4))) float f32x4;
typedef __attribute__((ext_vector_type(16))) float f32x16;
typedef __attribute__((ext_vector_type(4))) unsigned int u32x4;

__device__ __forceinline__ short f2bf(float f) {
    union { float f; uint32_t u; } x; x.f = f;
    uint32_t r = x.u + 0x7fffu + ((x.u >> 16) & 1u);   // RNE
    return (short)(r >> 16);
}

__device__ __forceinline__ unsigned int cvt_pk_bf16(float lo, float hi) {
    unsigned int r;
    asm("v_cvt_pk_bf16_f32 %0, %1, %2" : "=v"(r) : "v"(lo), "v"(hi));
    return r;
}

// swap: a.hi32lanes <-> b.lo32lanes  (one instr fills two exchange words)
__device__ __forceinline__ void permswap(unsigned int& a, unsigned int& b) {
    asm volatile("v_permlane32_swap_b32 %0, %1" : "+v"(a), "+v"(b));
}

// async global->LDS, 16B per lane. LDS dest is wave-uniform base + lane*16.
__device__ __forceinline__ void gload_lds16(const void* g, void* l) {
    __builtin_amdgcn_global_load_lds(
        (const __attribute__((address_space(1))) unsigned int*)g,
        (__attribute__((address_space(3))) unsigned int*)l, 16, 0, 0);
}

// ---------------- fused prep: x->bf16, w_qkv^T, w_out^T (one launch) ----------
// blocks [0,3072): convert x; [3072,3504): transpose w_qkv; [3504,3648): w_out.
__global__ __launch_bounds__(256) void prep(
    const float* __restrict__ x, short* __restrict__ Xbf,
    const float* __restrict__ w_qkv, short* __restrict__ wqkvT,
    const float* __restrict__ w_out, short* __restrict__ woutT) {
    __shared__ float tile[64][65];
    const int tid = threadIdx.x;
    const int bidx = blockIdx.x;
    if (bidx < 3072) {
        size_t i = ((size_t)bidx * 256 + tid) * 8;
        float4 a = *reinterpret_cast<const float4*>(x + i);
        float4 b = *reinterpret_cast<const float4*>(x + i + 4);
        bf16x8 v;
        v[0] = f2bf(a.x); v[1] = f2bf(a.y); v[2] = f2bf(a.z); v[3] = f2bf(a.w);
        v[4] = f2bf(b.x); v[5] = f2bf(b.y); v[6] = f2bf(b.z); v[7] = f2bf(b.w);
        *reinterpret_cast<bf16x8*>(Xbf + i) = v;
        return;
    }
    const float* in;
    short* out;
    int R, C, c0, r0;
    if (bidx < 3504) {
        int bid = bidx - 3072;                 // 36 x 12
        in = w_qkv; out = wqkvT; R = 768; C = 2304;
        c0 = (bid % 36) * 64; r0 = (bid / 36) * 64;
    } else {
        int bid = bidx - 3504;                 // 12 x 12
        in = w_out; out = woutT; R = 768; C = 768;
        c0 = (bid % 12) * 64; r0 = (bid / 12) * 64;
    }
#pragma unroll
    for (int i = 0; i < 16; ++i) {
        int e = tid + 256 * i;
        int r = e >> 6, c = e & 63;
        tile[r][c] = in[(size_t)(r0 + r) * C + c0 + c];
    }
    __syncthreads();
#pragma unroll
    for (int i = 0; i < 16; ++i) {
        int e = tid + 256 * i;
        int rr = e >> 6, cc = e & 63;
        out[(size_t)(c0 + rr) * R + r0 + cc] = f2bf(tile[cc][rr]);
    }
}

// ---------------- GEMM1: Xbf(bf16) @ w_qkvT -> Q,K,Vt (bf16) ----------------
// 128x128 tile, 512 threads / 8 waves (4M x 2N, 32x64 per wave), 64KB dbuf LDS,
// counted vmcnt(4) pipeline.
__global__ __launch_bounds__(512) void gemm_qkv(
    const short* __restrict__ A, const short* __restrict__ Bt,
    const float* __restrict__ bias,
    short* __restrict__ Qo, short* __restrict__ Ko, short* __restrict__ Vto) {
    __shared__ __align__(16) char smem[65536];   // [p][A 16KB | B 16KB]; epilogue reuses 32KB
    const int tid = threadIdx.x;
    const int lane = tid & 63;
    const int wid = tid >> 6;            // 0..7
    const int wm = wid >> 1, wn = wid & 1;
    // bijective XCD-chunked swizzle: nwg=1152, 144/chunk, n-fast.
    const int bid = blockIdx.x;
    const int wg = (bid & 7) * 144 + (bid >> 3);
    const int mb = wg / 18, nb = wg - mb * 18;
    const int m0 = mb * 128;
    const int n0 = nb * 128;

    const f32x4 zero4 = {0.f, 0.f, 0.f, 0.f};
    f32x4 acc[2][4];
#pragma unroll
    for (int i = 0; i < 2; ++i)
#pragma unroll
        for (int j = 0; j < 4; ++j) acc[i][j] = zero4;

    const short* Ab = A + (size_t)m0 * EMBED;
    const short* Bb = Bt + (size_t)n0 * EMBED;

    auto stage = [&](int p, int kt) {   // 4 vmem instrs/thread (512 threads)
        const int k0 = kt * 64;
        char* base = smem + p * 32768;
#pragma unroll
        for (int i = 0; i < 2; ++i) {
            int e = i * 512 + tid;
            int r = e >> 3, cs = (e & 7) ^ (r & 7);
            char* dst = base + (size_t)(i * 512 + wid * 64) * 16;
            gload_lds16(Ab + (size_t)r * EMBED + k0 + cs * 8, dst);
            gload_lds16(Bb + (size_t)r * EMBED + k0 + cs * 8, dst + 16384);
        }
    };

    stage(0, 0);
    stage(1, 1);
    asm volatile("s_waitcnt vmcnt(4)" ::: "memory");   // buf0 landed
    __builtin_amdgcn_s_barrier();
    __builtin_amdgcn_sched_barrier(0);

    for (int t = 0; t < 12; ++t) {
        const int p = t & 1;
        const char* As = smem + p * 32768;
        const char* Bs = As + 16384;
        bf16x8 af[2][2], bfv[4][2];
#pragma unroll
        for (int mi = 0; mi < 2; ++mi)
#pragma unroll
            for (int kh = 0; kh < 2; ++kh) {
                int row = wm * 32 + mi * 16 + (lane & 15);
                int c = kh * 4 + (lane >> 4);
                af[mi][kh] = *reinterpret_cast<const bf16x8*>(
                    As + row * 128 + (((c ^ (row & 7))) << 4));
            }
#pragma unroll
        for (int ni = 0; ni < 4; ++ni)
#pragma unroll
            for (int kh = 0; kh < 2; ++kh) {
                int row = wn * 64 + ni * 16 + (lane & 15);
                int c = kh * 4 + (lane >> 4);
                bfv[ni][kh] = *reinterpret_cast<const bf16x8*>(
                    Bs + row * 128 + (((c ^ (row & 7))) << 4));
            }
        asm volatile("s_waitcnt lgkmcnt(0)" ::: "memory");   // my reads of buf[p] done
        __builtin_amdgcn_s_barrier();                        // everyone's reads done
        __builtin_amdgcn_sched_barrier(0);
        if (t + 2 < 12) stage(p, t + 2);                     // refill freed buffer

        __builtin_amdgcn_s_setprio(1);
#pragma unroll
        for (int mi = 0; mi < 2; ++mi)
#pragma unroll
            for (int ni = 0; ni < 4; ++ni)
#pragma unroll
                for (int kh = 0; kh < 2; ++kh)
                    acc[mi][ni] = __builtin_amdgcn_mfma_f32_16x16x32_bf16(
                        af[mi][kh], bfv[ni][kh], acc[mi][ni], 0, 0, 0);
        __builtin_amdgcn_s_setprio(0);

        if (t + 2 < 12)
            asm volatile("s_waitcnt vmcnt(4)" ::: "memory"); // tile t+1 landed, t+2 in flight
        else
            asm volatile("s_waitcnt vmcnt(0)" ::: "memory"); // tail drain
        __builtin_amdgcn_s_barrier();                        // tile t+1 visible to all
        __builtin_amdgcn_sched_barrier(0);
    }

    // epilogue. s (qkv selector) is block-constant: nb/6.
    const int s = nb / 6;
    const int bb = m0 >> 10;
    if (s == 2) {
        // V: transpose 128x128 tile through LDS (XOR-swizzled), then store
        // rows of Vt [bh*64+d][tok] as 256B-contiguous segments.
        char* T = smem;
#pragma unroll
        for (int mi = 0; mi < 2; ++mi)
#pragma unroll
            for (int ni = 0; ni < 4; ++ni)
#pragma unroll
                for (int rp = 0; rp < 2; ++rp) {
                    int ml = wm * 32 + mi * 16 + ((lane >> 4) << 2) + rp * 2;
                    int nl = wn * 64 + ni * 16 + (lane & 15);
                    float bsv = bias[n0 + nl];
                    unsigned int w = cvt_pk_bf16(acc[mi][ni][rp * 2] + bsv,
                                                 acc[mi][ni][rp * 2 + 1] + bsv);
                    *reinterpret_cast<unsigned int*>(
                        T + nl * 256 + ((ml * 2) ^ ((nl & 7) << 4))) = w;
                }
        __syncthreads();
        // tok base is per-batch: m0 & 1023
        short* Vrow0 = Vto + ((size_t)bb * 768 + (nb - 12) * 128) * SEQ + (m0 & 1023);
#pragma unroll
        for (int it = 0; it < 4; ++it) {
            int chunk = it * 512 + tid;
            int row = chunk >> 4, k = chunk & 15;
            u32x4 v = *reinterpret_cast<const u32x4*>(
                T + row * 256 + ((k * 16) ^ ((row & 7) << 4)));
            *reinterpret_cast<u32x4*>(Vrow0 + (size_t)row * SEQ + k * 8) = v;
        }
    } else {
        short* dst = (s == 0) ? Qo : Ko;
        const float qs = (s == 0) ? 0.18033688f : 1.0f;   // SCALER*LOG2E for Q
        const int rem0 = n0 - s * 768;
#pragma unroll
        for (int mi = 0; mi < 2; ++mi)
#pragma unroll
            for (int ni = 0; ni < 4; ++ni)
#pragma unroll
                for (int r = 0; r < 4; ++r) {
                    int m = m0 + wm * 32 + mi * 16 + ((lane >> 4) << 2) + r;
                    int nl = wn * 64 + ni * 16 + (lane & 15);
                    int rem = rem0 + nl;
                    int h = rem >> 6, d = rem & 63;
                    int tok = m & 1023;
                    float v = (acc[mi][ni][r] + bias[n0 + nl]) * qs;
                    dst[(((size_t)(bb * NHEADS + h)) * SEQ + tok) * HDIM + d] = f2bf(v);
                }
    }
}

// ---------------- flash attention: 2-wave, 64 q/wave, 3-buf, A/B phase pipeline --
// Q,K: [BH][SEQ][64] bf16 (Q pre-scaled by 0.125*log2e); Vt: [BH][64][SEQ] bf16.
// grid (96 bh, 8 qt), 128 threads. Per iter: QK(A), QK(B), then
// {exp2/pack A -> PV(A)} and {exp2/pack B -> PV(B)} so each group's VALU phase
// sits adjacent to the other group's independent MFMA phase (in-wave overlap).
__global__ __launch_bounds__(128, 2) void attn_kernel(
    const short* __restrict__ Q, const short* __restrict__ K,
    const short* __restrict__ Vt, short* __restrict__ Xo) {
    __shared__ __align__(16) char smem[49152];   // K bufs 3x8KB @0; V bufs 3x8KB @24576
    const int tid = threadIdx.x, lane = tid & 63, wid = tid >> 6;   // wid 0..1
    const int l31 = lane & 31, g = lane >> 5;
    const int bh = blockIdx.x, qt = blockIdx.y;
    const int b = bh / NHEADS, h = bh - b * NHEADS;
    const short* Qh = Q + (size_t)bh * SEQ * HDIM;
    const short* Kh = K + (size_t)bh * SEQ * HDIM;
    const short* Vh = Vt + (size_t)bh * HDIM * SEQ;
    const int q0 = qt * 128 + wid * 64;
    const int swz = (l31 & 7);

    const f32x16 zero16 = 0.f;
    bf16x8 qf[2][4];   // two q-groups of 32
#pragma unroll
    for (int qg = 0; qg < 2; ++qg)
#pragma unroll
        for (int ds = 0; ds < 4; ++ds)
            qf[qg][ds] = *reinterpret_cast<const bf16x8*>(
                Qh + (size_t)(q0 + qg * 32 + l31) * HDIM + ds * 16 + g * 8);

    f32x16 oA0 = zero16, oA1 = zero16, oB0 = zero16, oB1 = zero16;
    float lA = 0.f, lB = 0.f;

    auto stage = [&](int buf, int j0) {   // 8 vmem instrs/thread (128 threads)
#pragma unroll
        for (int i = 0; i < 4; ++i) {
            int e = i * 128 + tid;
            int r = e >> 3, cs = (e & 7) ^ (r & 7);
            char* dst = smem + (size_t)(i * 128 + wid * 64) * 16 + buf * 8192;
            gload_lds16(Kh + (size_t)(j0 + r) * HDIM + cs * 8, dst);
            gload_lds16(Vh + (size_t)r * SEQ + j0 + cs * 8, dst + 24576);
        }
    };

    stage(0, 0);
    stage(1, 64);

    for (int t = 0; t < 16; ++t) {
        const int bsel = t % 3;
        if (t < 15)
            asm volatile("s_waitcnt vmcnt(8)" ::: "memory");   // tile t landed
        else
            asm volatile("s_waitcnt vmcnt(0)" ::: "memory");
        __builtin_amdgcn_s_barrier();
        __builtin_amdgcn_sched_barrier(0);

        const char* kb = smem + bsel * 8192;
        const char* vb = smem + 24576 + bsel * 8192;

        // K + V frags (shared across both q-groups), then prefetch
        bf16x8 kf[2][4];
#pragma unroll
        for (int s = 0; s < 2; ++s)
#pragma unroll
            for (int ds = 0; ds < 4; ++ds)
                kf[s][ds] = *reinterpret_cast<const bf16x8*>(
                    kb + (s * 32 + l31) * 128 + (((ds * 2 + g) ^ swz) << 4));
        bf16x8 vf[4][2];
#pragma unroll
        for (int kst = 0; kst < 4; ++kst)
#pragma unroll
            for (int dsub = 0; dsub < 2; ++dsub)
                vf[kst][dsub] = *reinterpret_cast<const bf16x8*>(
                    vb + (dsub * 32 + l31) * 128 + (((kst * 2 + g) ^ swz) << 4));
        __builtin_amdgcn_sched_barrier(0);   // pin: reads issued before stage
        if (t + 2 < 16) stage((t + 2) % 3, (t + 2) * 64);

        // QK^T group A, then group B (independent chains)
        f32x16 sA0 = zero16, sA1 = zero16;
        __builtin_amdgcn_s_setprio(1);
#pragma unroll
        for (int ds = 0; ds < 4; ++ds) {
            sA0 = __builtin_amdgcn_mfma_f32_32x32x16_bf16(kf[0][ds], qf[0][ds], sA0, 0, 0, 0);
            sA1 = __builtin_amdgcn_mfma_f32_32x32x16_bf16(kf[1][ds], qf[0][ds], sA1, 0, 0, 0);
        }
        __builtin_amdgcn_s_setprio(0);
        f32x16 sB0 = zero16, sB1 = zero16;
        __builtin_amdgcn_s_setprio(1);
#pragma unroll
        for (int ds = 0; ds < 4; ++ds) {
            sB0 = __builtin_amdgcn_mfma_f32_32x32x16_bf16(kf[0][ds], qf[1][ds], sB0, 0, 0, 0);
            sB1 = __builtin_amdgcn_mfma_f32_32x32x16_bf16(kf[1][ds], qf[1][ds], sB1, 0, 0, 0);
        }
        __builtin_amdgcn_s_setprio(0);

        // ---- group A: exp2 + sum + pack + PV (overlaps QK-B / exp2-B) ----
        float rsA = 0.f;
#pragma unroll
        for (int r = 0; r < 16; ++r) {
            float a0 = __builtin_amdgcn_exp2f(sA0[r]);
            float a1 = __builtin_amdgcn_exp2f(sA1[r]);
            sA0[r] = a0; sA1[r] = a1; rsA += a0 + a1;
        }
        lA += rsA;
        bf16x8 pfA[4];
#pragma unroll
        for (int s = 0; s < 2; ++s) {
            const f32x16& sv = s ? sA1 : sA0;
            unsigned int pk[8];
#pragma unroll
            for (int j = 0; j < 8; ++j) pk[j] = cvt_pk_bf16(sv[2 * j], sv[2 * j + 1]);
            permswap(pk[0], pk[2]); permswap(pk[1], pk[3]);
            permswap(pk[4], pk[6]); permswap(pk[5], pk[7]);
            u32x4 wlo, whi;
            wlo[0] = pk[0]; wlo[1] = pk[1]; wlo[2] = pk[2]; wlo[3] = pk[3];
            whi[0] = pk[4]; whi[1] = pk[5]; whi[2] = pk[6]; whi[3] = pk[7];
            pfA[s * 2 + 0] = __builtin_bit_cast(bf16x8, wlo);
            pfA[s * 2 + 1] = __builtin_bit_cast(bf16x8, whi);
        }
        __builtin_amdgcn_s_setprio(1);
#pragma unroll
        for (int kst = 0; kst < 4; ++kst) {
            oA0 = __builtin_amdgcn_mfma_f32_32x32x16_bf16(vf[kst][0], pfA[kst], oA0, 0, 0, 0);
            oA1 = __builtin_amdgcn_mfma_f32_32x32x16_bf16(vf[kst][1], pfA[kst], oA1, 0, 0, 0);
        }
        __builtin_amdgcn_s_setprio(0);

        // ---- group B: exp2 + sum + pack + PV (overlaps PV-A) ----
        float rsB = 0.f;
#pragma unroll
        for (int r = 0; r < 16; ++r) {
            float b0 = __builtin_amdgcn_exp2f(sB0[r]);
            float b1 = __builtin_amdgcn_exp2f(sB1[r]);
            sB0[r] = b0; sB1[r] = b1; rsB += b0 + b1;
        }
        lB += rsB;
        bf16x8 pfB[4];
#pragma unroll
        for (int s = 0; s < 2; ++s) {
            const f32x16& sv = s ? sB1 : sB0;
            unsigned int pk[8];
#pragma unroll
            for (int j = 0; j < 8; ++j) pk[j] = cvt_pk_bf16(sv[2 * j], sv[2 * j + 1]);
            permswap(pk[0], pk[2]); permswap(pk[1], pk[3]);
            permswap(pk[4], pk[6]); permswap(pk[5], pk[7]);
            u32x4 wlo, whi;
            wlo[0] = pk[0]; wlo[1] = pk[1]; wlo[2] = pk[2]; wlo[3] = pk[3];
            whi[0] = pk[4]; whi[1] = pk[5]; whi[2] = pk[6]; whi[3] = pk[7];
            pfB[s * 2 + 0] = __builtin_bit_cast(bf16x8, wlo);
            pfB[s * 2 + 1] = __builtin_bit_cast(bf16x8, whi);
        }
        __builtin_amdgcn_s_setprio(1);
#pragma unroll
        for (int kst = 0; kst < 4; ++kst) {
            oB0 = __builtin_amdgcn_mfma_f32_32x32x16_bf16(vf[kst][0], pfB[kst], oB0, 0, 0, 0);
            oB1 = __builtin_amdgcn_mfma_f32_32x32x16_bf16(vf[kst][1], pfB[kst], oB1, 0, 0, 0);
        }
        __builtin_amdgcn_s_setprio(0);
    }

    lA += __shfl_xor(lA, 32);
    lB += __shfl_xor(lB, 32);
    const float rlA = 1.0f / lA, rlB = 1.0f / lB;

    // ---- O epilogue: transpose through LDS, then coalesced 16B stores ----
    __syncthreads();                         // all waves done with K/V buffers
    char* T = smem;                          // 16KB: [128 q][64 d] bf16, swizzled
    {
        const int qx = (l31 & 7) << 4;
#pragma unroll
        for (int qg = 0; qg < 2; ++qg) {
            char* Tw = T + (wid * 64 + qg * 32 + l31) * 128;
            const float rl = qg ? rlB : rlA;
#pragma unroll
            for (int half = 0; half < 2; ++half) {
                const f32x16& ov = qg ? (half ? oB1 : oB0) : (half ? oA1 : oA0);
#pragma unroll
                for (int j = 0; j < 8; ++j) {
                    unsigned int w = cvt_pk_bf16(ov[2 * j] * rl, ov[2 * j + 1] * rl);
                    int off = 4 * (j & 1) + 16 * (j >> 1) + 8 * g + 64 * half;
                    *reinterpret_cast<unsigned int*>(Tw + (off ^ qx)) = w;
                }
            }
        }
    }
    __syncthreads();
    const int q0b = qt * 128;
    short* xbase = Xo + ((size_t)b * SEQ + q0b) * EMBED + h * HDIM;
#pragma unroll
    for (int it = 0; it < 8; ++it) {
        int chunk = it * 128 + tid;
        int row = chunk >> 3, k = chunk & 7;
        u32x4 v = *reinterpret_cast<const u32x4*>(
            T + row * 128 + ((k * 16) ^ ((row & 7) << 4)));
        *reinterpret_cast<u32x4*>(xbase + (size_t)row * EMBED + k * 8) = v;
    }
}

// ---------------- GEMM3: xattn(bf16) @ w_outT -> out (fp32) ----------------
// BM=128, BN=64: 768 blocks (exactly 3/CU), 48KB LDS dbuf, counted vmcnt(6).
__global__ __launch_bounds__(256) void gemm_out(
    const short* __restrict__ A, const short* __restrict__ Bt,
    const float* __restrict__ bias, float* __restrict__ C) {
    __shared__ __align__(16) char smem[49152];   // [p][A 16KB | B 8KB]
    const int tid = threadIdx.x;
    const int lane = tid & 63;
    const int wid = tid >> 6;
    const int wm = wid >> 1, wn = wid & 1;
    // bijective XCD-chunked swizzle: nwg=768, 96/chunk, n-fast (nb=12).
    const int bid = blockIdx.x;
    const int wg = (bid & 7) * 96 + (bid >> 3);
    const int mb = wg / 12, nb = wg - mb * 12;
    const int m0 = mb * 128;
    const int n0 = nb * 64;

    const f32x4 zero4 = {0.f, 0.f, 0.f, 0.f};
    f32x4 acc[4][2];
#pragma unroll
    for (int i = 0; i < 4; ++i)
#pragma unroll
        for (int j = 0; j < 2; ++j) acc[i][j] = zero4;

    const short* Ab = A + (size_t)m0 * EMBED;
    const short* Bb = Bt + (size_t)n0 * EMBED;

    auto stage = [&](int p, int kt) {   // 6 vmem instrs/thread
        const int k0 = kt * 64;
        char* base = smem + p * 24576;
#pragma unroll
        for (int i = 0; i < 4; ++i) {   // A: 128 rows x 64 cols
            int e = i * 256 + tid;
            int r = e >> 3, cs = (e & 7) ^ (r & 7);
            gload_lds16(Ab + (size_t)r * EMBED + k0 + cs * 8,
                        base + (size_t)(i * 256 + wid * 64) * 16);
        }
#pragma unroll
        for (int i = 0; i < 2; ++i) {   // B: 64 rows x 64 cols
            int e = i * 256 + tid;
            int r = e >> 3, cs = (e & 7) ^ (r & 7);
            gload_lds16(Bb + (size_t)r * EMBED + k0 + cs * 8,
                        base + 16384 + (size_t)(i * 256 + wid * 64) * 16);
        }
    };

    stage(0, 0);
    stage(1, 1);
    asm volatile("s_waitcnt vmcnt(6)" ::: "memory");   // buf0 landed
    __builtin_amdgcn_s_barrier();
    __builtin_amdgcn_sched_barrier(0);

    for (int t = 0; t < 12; ++t) {
        const int p = t & 1;
        const char* As = smem + p * 24576;
        const char* Bs = As + 16384;
        bf16x8 af[4][2], bfv[2][2];
#pragma unroll
        for (int mi = 0; mi < 4; ++mi)
#pragma unroll
            for (int kh = 0; kh < 2; ++kh) {
                int row = wm * 64 + mi * 16 + (lane & 15);
                int c = kh * 4 + (lane >> 4);
                af[mi][kh] = *reinterpret_cast<const bf16x8*>(
                    As + row * 128 + (((c ^ (row & 7))) << 4));
            }
#pragma unroll
        for (int ni = 0; ni < 2; ++ni)
#pragma unroll
            for (int kh = 0; kh < 2; ++kh) {
                int row = wn * 32 + ni * 16 + (lane & 15);
                int c = kh * 4 + (lane >> 4);
                bfv[ni][kh] = *reinterpret_cast<const bf16x8*>(
                    Bs + row * 128 + (((c ^ (row & 7))) << 4));
            }
        asm volatile("s_waitcnt lgkmcnt(0)" ::: "memory");
        __builtin_amdgcn_s_barrier();
        __builtin_amdgcn_sched_barrier(0);
        if (t + 2 < 12) stage(p, t + 2);

        __builtin_amdgcn_s_setprio(1);
#pragma unroll
        for (int mi = 0; mi < 4; ++mi)
#pragma unroll
            for (int ni = 0; ni < 2; ++ni)
#pragma unroll
                for (int kh = 0; kh < 2; ++kh)
                    acc[mi][ni] = __builtin_amdgcn_mfma_f32_16x16x32_bf16(
                        af[mi][kh], bfv[ni][kh], acc[mi][ni], 0, 0, 0);
        __builtin_amdgcn_s_setprio(0);

        if (t + 2 < 12)
            asm volatile("s_waitcnt vmcnt(6)" ::: "memory");
        else
            asm volatile("s_waitcnt vmcnt(0)" ::: "memory");
        __builtin_amdgcn_s_barrier();
        __builtin_amdgcn_sched_barrier(0);
    }

#pragma unroll
    for (int mi = 0; mi < 4; ++mi)
#pragma unroll
        for (int ni = 0; ni < 2; ++ni)
#pragma unroll
            for (int r = 0; r < 4; ++r) {
                int m = m0 + wm * 64 + mi * 16 + ((lane >> 4) << 2) + r;
                int n = n0 + wn * 32 + ni * 16 + (lane & 15);
                C[(size_t)m * EMBED + n] = acc[mi][ni][r] + bias[n];
            }
}

// ---------------- launch ----------------
extern "C" void kernel_launch(void* const* d_in, const int* in_sizes, int n_in,
                              void* d_out, int out_size, void* d_ws, size_t ws_size,
                              hipStream_t stream) {
    const float* x      = (const float*)d_in[0];
    const float* w_qkv  = (const float*)d_in[1];
    const float* b_qkv  = (const float*)d_in[2];
    const float* w_out  = (const float*)d_in[3];
    const float* b_out  = (const float*)d_in[4];
    float* out = (float*)d_out;
    char* ws = (char*)d_ws;

    short* wqkvT = (short*)(ws + 0);            //  2304*768*2
    short* woutT = (short*)(ws + 3538944);      //   768*768*2
    short* Qb    = (short*)(ws + 4718592);      // 96*1024*64*2 each
    short* Kb    = (short*)(ws + 17301504);
    short* Vtb   = (short*)(ws + 29884416);
    short* Xbf   = (short*)(ws + 42467328);     // x as bf16 (prep..gemm1), then
    short* Xab   = (short*)(ws + 42467328);     // reused as attn output

    prep<<<dim3(3648), 256, 0, stream>>>(x, Xbf, w_qkv, wqkvT, w_out, woutT);
    gemm_qkv<<<dim3(1152), 512, 0, stream>>>(Xbf, wqkvT, b_qkv, Qb, Kb, Vtb);
    attn_kernel<<<dim3(96, 8), 128, 0, stream>>>(Qb, Kb, Vtb, Xab);
    gemm_out<<<dim3(768), 256, 0, stream>>>(Xab, woutT, b_out, out);
}